// Round 2
// baseline (137.345 us; speedup 1.0000x reference)
//
#include <hip/hip_runtime.h>

// Z: (2049, 8193) fp32, alpha: (1,) fp32.
// out = Z, except last row: out[2048, j] = Z[2048,j] + (alpha/N) * sum_{c<D} v[c]*(Z[c+D,j]-Z[c,j])
// where v[c] = sum_{j<N} Z[2048, j] * Z[c, j]   (j < N only: M kills column N)

#define D   1024
#define N   8192
#define DD  2049
#define N1  8193

#define TOTAL_DW 16787457L   // 2049*8193 dwords in Z/out
#define TOTAL_Q  4196864     // aligned quads; 1 tail dword extra

#define NSPLIT  64           // c-splits for the correction partials
#define PSTRIDE 8196         // padded partial row stride (dwords), 16B-aligned rows

typedef float f32x4u __attribute__((ext_vector_type(4), aligned(4)));   // may be misaligned (row phase r%4)
typedef float f32x4a __attribute__((ext_vector_type(4), aligned(16)));  // provably 16B-aligned

// ---------------- Kernel A: v[c] = dot(Z[c,:8192], Z[2048,:8192]) ----------------
// 1024 blocks x 512 threads, one row per block. Reads 32.5 MB (cold). Row loads may be
// misaligned (phase c%4) -> compiler splits; acceptable at this volume. u loads aligned.
__global__ void __launch_bounds__(512) vdot_rows(const float* __restrict__ Z,
                                                 float* __restrict__ v) {
    const int c = blockIdx.x;
    const int t = threadIdx.x;
    const float* __restrict__ row = Z + (long)c * N1;
    const float* __restrict__ u   = Z + (long)(DD - 1) * N1;   // 2048*8193 % 4 == 0 -> aligned
    float acc = 0.f;
    #pragma unroll
    for (int it = 0; it < 4; ++it) {
        const int q = t + it * 512;                 // quad 0..2047 -> j = 4q..4q+3 (j<8192)
        f32x4u a = *(const f32x4u*)(row + 4 * q);
        f32x4a b = *(const f32x4a*)(u   + 4 * q);
        acc += a.x * b.x + a.y * b.y + a.z * b.z + a.w * b.w;
    }
    #pragma unroll
    for (int off = 32; off > 0; off >>= 1)
        acc += __shfl_down(acc, off, 64);
    __shared__ float smem[8];
    if ((t & 63) == 0) smem[t >> 6] = acc;
    __syncthreads();
    if (t == 0) {
        float s = 0.f;
        #pragma unroll
        for (int w = 0; w < 8; ++w) s += smem[w];
        v[c] = s;
    }
}

// ---------------- Kernel B: flat aligned copy Z -> out ----------------
// Ignores row structure entirely: the (2049*8193)-dword array is copied as aligned quads.
// Every access is a full-width dwordx4; pure streaming at HBM BW. Z lands in L3 for K-C.
__global__ void __launch_bounds__(512) flat_copy(const float* __restrict__ Z,
                                                 float* __restrict__ out) {
    const int t = threadIdx.x;
    const long base = (long)blockIdx.x * 2048;      // 2048 quads per block
    #pragma unroll
    for (int it = 0; it < 4; ++it) {
        const long q = base + t + it * 512;
        if (q < TOTAL_Q) {
            f32x4a a = *(const f32x4a*)(Z + 4 * q);
            __builtin_nontemporal_store(a, (f32x4a*)(out + 4 * q));
        }
    }
    if (blockIdx.x == 0 && t == 0)
        out[TOTAL_DW - 1] = Z[TOTAL_DW - 1];        // tail dword (element [2048][8192])
}

// ---------------- Kernel C: correction partials (no atomics) ----------------
// grid = (8, 64): x covers 2048 quads (j=0..8191), y = 64 splits of 16 c's.
// Z rows are L3-resident after flat_copy (67 MB < 256 MB Infinity Cache).
__global__ void __launch_bounds__(256) corr_partial(const float* __restrict__ Z,
                                                    const float* __restrict__ v,
                                                    float* __restrict__ part) {
    const int q  = blockIdx.x * 256 + threadIdx.x;   // quad 0..2047
    const int j0 = q * 4;
    const int c0 = blockIdx.y * 16;
    float lx = 0.f, ly = 0.f, lz = 0.f, lw = 0.f;
    #pragma unroll
    for (int cc = 0; cc < 16; ++cc) {
        const int c = c0 + cc;
        const float vc = v[c];
        f32x4u zp = *(const f32x4u*)(Z + (long)(c + D) * N1 + j0);
        f32x4u zm = *(const f32x4u*)(Z + (long)c * N1 + j0);
        lx += vc * (zp.x - zm.x);
        ly += vc * (zp.y - zm.y);
        lz += vc * (zp.z - zm.z);
        lw += vc * (zp.w - zm.w);
    }
    f32x4a res = {lx, ly, lz, lw};
    __builtin_nontemporal_store(res, (f32x4a*)(part + (long)blockIdx.y * PSTRIDE + j0));
    // tail column j = 8192 (one thread per c-split)
    if (q == 0) {
        float lt = 0.f;
        #pragma unroll
        for (int cc = 0; cc < 16; ++cc) {
            const int c = c0 + cc;
            lt += v[c] * (Z[(long)(c + D) * N1 + N] - Z[(long)c * N1 + N]);
        }
        part[(long)blockIdx.y * PSTRIDE + N] = lt;
    }
}

// ---------------- Kernel D: finalize last row ----------------
// out[2048, j] = Z[2048, j] + scale * sum_{s<64} part[s][j], for all j=0..8192.
__global__ void __launch_bounds__(256) corr_finalize(const float* __restrict__ Z,
                                                     const float* __restrict__ part,
                                                     const float* __restrict__ alpha,
                                                     float* __restrict__ out) {
    const int tid = blockIdx.x * 256 + threadIdx.x;  // quad id 0..2048 (2048 = tail)
    if (tid > 2048) return;
    const float scale = alpha[0] / (float)N;
    const float* __restrict__ zl = Z   + (long)(DD - 1) * N1;    // 16B-aligned
    float*       __restrict__ o  = out + (long)(DD - 1) * N1;
    if (tid < 2048) {
        const int j0 = tid * 4;
        float sx = 0.f, sy = 0.f, sz = 0.f, sw = 0.f;
        #pragma unroll
        for (int s = 0; s < NSPLIT; ++s) {
            f32x4a p = *(const f32x4a*)(part + (long)s * PSTRIDE + j0);
            sx += p.x; sy += p.y; sz += p.z; sw += p.w;
        }
        f32x4a z = *(const f32x4a*)(zl + j0);
        f32x4a r = {z.x + scale * sx, z.y + scale * sy, z.z + scale * sz, z.w + scale * sw};
        *(f32x4a*)(o + j0) = r;
    } else {
        float s = 0.f;
        #pragma unroll
        for (int ss = 0; ss < NSPLIT; ++ss) s += part[(long)ss * PSTRIDE + N];
        o[N] = zl[N] + scale * s;
    }
}

extern "C" void kernel_launch(void* const* d_in, const int* in_sizes, int n_in,
                              void* d_out, int out_size, void* d_ws, size_t ws_size,
                              hipStream_t stream) {
    const float* Z     = (const float*)d_in[0];
    const float* alpha = (const float*)d_in[1];
    float* out  = (float*)d_out;
    float* v    = (float*)d_ws;                 // D floats = 4 KB scratch
    float* part = (float*)d_ws + 1024;          // 64 x 8196 floats = 2.1 MB, 16B-aligned

    vdot_rows   <<<1024, 512, 0, stream>>>(Z, v);
    flat_copy   <<<2050, 512, 0, stream>>>(Z, out);
    corr_partial<<<dim3(8, 64), 256, 0, stream>>>(Z, v, part);
    corr_finalize<<<9, 256, 0, stream>>>(Z, part, alpha, out);
}

// Round 3
// 132.578 us; speedup vs baseline: 1.0360x; 1.0360x over previous
//
#include <hip/hip_runtime.h>

// Z: (2049, 8193) fp32, alpha: (1,) fp32.
// out = Z, except last row: out[2048, j] = Z[2048,j] + (alpha/N) * sum_{c<D} v[c]*(Z[c+D,j]-Z[c,j])
// where v[c] = sum_{j<N} Z[2048, j] * Z[c, j]   (j < N only: M kills column N)
//
// Alignment strategy: rows start at dword r*8193 (phase r mod 4), so row-indexed f32x4
// accesses split 4x at the VMEM issuer. Every bulk loop below uses provably 16B-aligned
// dwordx4 accesses:
//   - copy+dot runs on the FLAT dword index (always aligned); u[j] comes from 4
//     pre-shifted aligned copies S_phi[k] = u[k+phi].
//   - correction groups c by residue class mod 4 (D == 0 mod 4 -> zp/zm share phase)
//     and shifts the j-grid by phi so Z loads are aligned.

#define D   1024
#define N   8192
#define DD  2049
#define N1  8193
#define TOTAL_DW 16787457u   // 2049*8193
#define TOTAL_Q  4196864u    // full aligned quads; +1 tail dword

#define NSPLIT  64
#define PSTRIDE 8196         // partial row stride (dwords); holds j up to 8194 overrun

// ws layout (floats): v[1024] | S[4][8192] | part[64][8196]
#define WS_V    0
#define WS_S    1024
#define WS_PART (1024 + 4*8192)

typedef float f32x4a __attribute__((ext_vector_type(4), aligned(16)));
typedef float f32x4u __attribute__((ext_vector_type(4), aligned(4)));

// ---------------- Kernel 0: prep — zero v, build 4 shifted aligned copies of u ----------------
__global__ void __launch_bounds__(1024) prep(const float* __restrict__ Z,
                                             float* __restrict__ ws) {
    const uint t = threadIdx.x, b = blockIdx.x;
    const float* __restrict__ u = Z + (size_t)(DD - 1) * N1;
    if (b == 0) ws[WS_V + t] = 0.f;
    const uint gid = b * 1024u + t;          // 0..32767
    const uint p = gid >> 13, k = gid & 8191u;
    ws[WS_S + (p << 13) + k] = (k + p <= (uint)N) ? u[k + p] : 0.f;
}

// ---------------- Kernel 1: fused flat copy + dot ----------------
// grid = 2050 x 512. Flat aligned quads: copy Z->out, and for rows r<1024 accumulate
// v[r] += Z[r,j]*u[j] (j<8192) using the shifted-u copies. Block spans <=2 rows ->
// two accumulators + 2 atomics. Z read exactly once from HBM.
__global__ void __launch_bounds__(512) copy_dot_flat(const float* __restrict__ Z,
                                                     float* __restrict__ out,
                                                     float* __restrict__ ws) {
    const uint b = blockIdx.x, t = threadIdx.x;
    const float* __restrict__ Spool = ws + WS_S;
    const float* __restrict__ u = Z + (size_t)(DD - 1) * N1;
    const uint rA   = (b * 8192u) / 8193u;        // row of block's first dword
    const uint bndB = (rA + 1u) * 8193u;          // dword where row rA+1 starts
    const bool dotBlk = (rA < (uint)D);
    float accA = 0.f, accB = 0.f;

    #pragma unroll
    for (int it = 0; it < 4; ++it) {
        const uint q = b * 2048u + t + it * 512u;
        if (q >= TOTAL_Q) continue;               // only last block clips
        const uint g0 = q * 4u;                   // dword index, 16B-aligned
        f32x4a a = *(const f32x4a*)(Z + g0);
        __builtin_nontemporal_store(a, (f32x4a*)(out + g0));
        if (dotBlk) {
            const uint r = g0 / 8193u;            // magic-mul division
            if (r < (uint)D) {
                const uint j0 = g0 - r * 8193u;
                if (j0 + 3u < 8193u) {            // quad fully inside row r
                    const uint phi = j0 & 3u;
                    const f32x4a s = *(const f32x4a*)(Spool + (phi << 13) + (j0 - phi));
                    float dsum = a.x * s.x + a.y * s.y + a.z * s.z;
                    if (j0 + 3u < 8192u) dsum += a.w * s.w;   // exclude j==8192
                    if (r == rA) accA += dsum; else accB += dsum;
                } else {                          // quad crosses the row boundary (rare)
                    const float ae[4] = {a.x, a.y, a.z, a.w};
                    #pragma unroll
                    for (int e = 0; e < 4; ++e) {
                        uint rr = r, j = j0 + (uint)e;
                        if (j > (uint)N) { rr = r + 1u; j -= (uint)N1; }
                        if (rr < (uint)D && j < (uint)N) {
                            const float dv = ae[e] * u[j];
                            if (rr == rA) accA += dv; else accB += dv;
                        }
                    }
                }
            }
        }
    }
    if (b == 0 && t == 0) out[TOTAL_DW - 1u] = Z[TOTAL_DW - 1u];  // tail dword

    if (dotBlk) {
        #pragma unroll
        for (int off = 32; off > 0; off >>= 1) {
            accA += __shfl_down(accA, off, 64);
            accB += __shfl_down(accB, off, 64);
        }
        __shared__ float smA[8], smB[8];
        if ((t & 63u) == 0u) { smA[t >> 6] = accA; smB[t >> 6] = accB; }
        __syncthreads();
        if (t == 0) {
            float sA = 0.f, sB = 0.f;
            #pragma unroll
            for (int w = 0; w < 8; ++w) { sA += smA[w]; sB += smB[w]; }
            atomicAdd(ws + WS_V + rA, sA);
            const uint rB = rA + 1u;
            if (rB < (uint)D && bndB < (b + 1u) * 8192u)
                atomicAdd(ws + WS_V + rB, sB);
        }
    }
}

// ---------------- Kernel 2: correction partials, phase-grouped (all loads aligned) ----------------
// grid = (8, 64) x 256. by -> residue class a = by>>4 (c = a mod 4), 16 c's per block.
// j-grid shifted by phi = (-a) mod 4 so every Z load is an aligned dwordx4.
// Z is L3-resident after kernel 1. Edge columns (<=3 per by) done scalar by one thread.
__global__ void __launch_bounds__(256) corr_partial(const float* __restrict__ Z,
                                                    const float* __restrict__ ws,
                                                    float* __restrict__ part) {
    const int t   = threadIdx.x;
    const int by  = blockIdx.y;
    const int a   = by >> 4;
    const int i   = by & 15;
    const int phi = (4 - a) & 3;
    const int j0  = phi + 4 * (blockIdx.x * 256 + t);   // (c*N1 + j0) % 4 == 0
    const float* __restrict__ v = ws + WS_V;
    float lx = 0.f, ly = 0.f, lz = 0.f, lw = 0.f;
    #pragma unroll
    for (int m = 0; m < 16; ++m) {
        const int c  = a + 64 * i + 4 * m;
        const float vc = v[c];
        f32x4a zp = *(const f32x4a*)(Z + (size_t)(c + D) * N1 + j0);
        f32x4a zm = *(const f32x4a*)(Z + (size_t)c * N1 + j0);
        lx += vc * (zp.x - zm.x);
        ly += vc * (zp.y - zm.y);
        lz += vc * (zp.z - zm.z);
        lw += vc * (zp.w - zm.w);
    }
    f32x4u res = {lx, ly, lz, lw};
    *(f32x4u*)(part + (size_t)by * PSTRIDE + j0) = res;  // may be split; 1 store per 32 loads
    if (blockIdx.x == 0 && t == 0) {
        // columns outside the shifted grid: {0..phi-1}, or {8192} when phi==0
        const int nj = (phi == 0) ? 1 : phi;
        for (int e = 0; e < nj; ++e) {
            const int j = (phi == 0) ? N : e;
            float s = 0.f;
            #pragma unroll
            for (int m = 0; m < 16; ++m) {
                const int c = a + 64 * i + 4 * m;
                s += v[c] * (Z[(size_t)(c + D) * N1 + j] - Z[(size_t)c * N1 + j]);
            }
            part[(size_t)by * PSTRIDE + j] = s;
        }
    }
}

// ---------------- Kernel 3: finalize last row ----------------
__global__ void __launch_bounds__(256) corr_finalize(const float* __restrict__ Z,
                                                     const float* __restrict__ part,
                                                     const float* __restrict__ alpha,
                                                     float* __restrict__ out) {
    const int tid = blockIdx.x * 256 + threadIdx.x;  // quad id 0..2048 (2048 = tail col)
    if (tid > 2048) return;
    const float scale = alpha[0] / (float)N;
    const float* __restrict__ zl = Z   + (size_t)(DD - 1) * N1;   // 16B-aligned
    float*       __restrict__ o  = out + (size_t)(DD - 1) * N1;
    if (tid < 2048) {
        const int j0 = tid * 4;
        float sx = 0.f, sy = 0.f, sz = 0.f, sw = 0.f;
        #pragma unroll
        for (int s = 0; s < NSPLIT; ++s) {
            f32x4a p = *(const f32x4a*)(part + (size_t)s * PSTRIDE + j0);
            sx += p.x; sy += p.y; sz += p.z; sw += p.w;
        }
        f32x4a z = *(const f32x4a*)(zl + j0);
        f32x4a r = {z.x + scale * sx, z.y + scale * sy, z.z + scale * sz, z.w + scale * sw};
        *(f32x4a*)(o + j0) = r;
    } else {
        float s = 0.f;
        #pragma unroll
        for (int ss = 0; ss < NSPLIT; ++ss) s += part[(size_t)ss * PSTRIDE + N];
        o[N] = zl[N] + scale * s;
    }
}

extern "C" void kernel_launch(void* const* d_in, const int* in_sizes, int n_in,
                              void* d_out, int out_size, void* d_ws, size_t ws_size,
                              hipStream_t stream) {
    const float* Z     = (const float*)d_in[0];
    const float* alpha = (const float*)d_in[1];
    float* out = (float*)d_out;
    float* ws  = (float*)d_ws;   // v | S | part  (~2.2 MB)

    prep         <<<32, 1024, 0, stream>>>(Z, ws);
    copy_dot_flat<<<2050, 512, 0, stream>>>(Z, out, ws);
    corr_partial <<<dim3(8, 64), 256, 0, stream>>>(Z, ws, ws + WS_PART);
    corr_finalize<<<9, 256, 0, stream>>>(Z, ws + WS_PART, alpha, out);
}